// Round 8
// baseline (4461.156 us; speedup 1.0000x reference)
//
#include <hip/hip_runtime.h>
#include <math.h>

#define NWG 128
#define TPB 1024

static constexpr int Bc=128, Ic=256, Hc=512, NCc=16, Tc=24, Mc=14;
static constexpr int Y_SZ  = Bc*NCc*Tc;     // 49152
static constexpr int P_OFF = Y_SZ;          // 49152
static constexpr int N_OFF = Y_SZ + Bc;     // 49280

// ws layout (floats) -- total 360448 floats = 1.375 MiB (proven budget)
static constexpr int XSZ    = Ic*Bc;                 // 32768
static constexpr int HSZ    = Hc*Bc;                 // 65536
static constexpr int PSZ    = Bc*Bc;                 // 16384
static constexpr int XS_OFF = 0;                     // xs[2][256][128]
static constexpr int HB_OFF = XS_OFF + 2*XSZ;        // hbuf[2][512][128]
static constexpr int SC_OFF = HB_OFF + 2*HSZ;        // stc[2][512][128]
static constexpr int HP_OFF = SC_OFF + 2*HSZ;        // hpp[2][128][128]

// Hierarchical barrier: 16 groups x 8 blocks; monotonic watermarks, 64B lines.
__device__ __align__(64) unsigned g_bcnt[16][16];
__device__ __align__(64) unsigned g_bgen[16][16];
__device__ __align__(64) unsigned g_brc[16];
__device__ __align__(64) unsigned g_brg[16];

__device__ __forceinline__ float sigm(float v){ return 1.0f/(1.0f+expf(-v)); }

// PRODUCER: system-scope write-through stores (sc0 sc1) -> coherent at IF.
__device__ __forceinline__ void gstore(float* p, float v){
  __hip_atomic_store(p, v, __ATOMIC_RELAXED, __HIP_MEMORY_SCOPE_SYSTEM);
}

// Barrier + CONSUMER-side acquire (r6-proven): after the generation barrier,
// one agent-scope acquire fence invalidates L1 + per-XCD L2, so subsequent
// PLAIN cached loads of cross-block data miss to the coherent IF and
// pipeline normally. Weights live in LDS, which the fence does NOT touch.
__device__ __forceinline__ void gsync(int w){
  __syncthreads();
  if (threadIdx.x == 0) {
    asm volatile("" ::: "memory");
    const int g = w >> 3;                    // 16 groups of 8
    unsigned prev = __hip_atomic_fetch_add(&g_bcnt[g][0], 1u, __ATOMIC_RELAXED, __HIP_MEMORY_SCOPE_SYSTEM);
    unsigned ep   = prev >> 3;               // barrier episode
    if ((prev & 7u) == 7u) {
      unsigned rprev = __hip_atomic_fetch_add(&g_brc[0], 1u, __ATOMIC_RELAXED, __HIP_MEMORY_SCOPE_SYSTEM);
      if ((rprev & 15u) == 15u) {
        __hip_atomic_store(&g_brg[0], (rprev >> 4) + 1u, __ATOMIC_RELEASE, __HIP_MEMORY_SCOPE_SYSTEM);
      } else {
        while ((int)(__hip_atomic_load(&g_brg[0], __ATOMIC_RELAXED, __HIP_MEMORY_SCOPE_SYSTEM) - (ep + 1u)) < 0)
          __builtin_amdgcn_s_sleep(1);
      }
      __hip_atomic_store(&g_bgen[g][0], ep + 1u, __ATOMIC_RELEASE, __HIP_MEMORY_SCOPE_SYSTEM);
    } else {
      while ((int)(__hip_atomic_load(&g_bgen[g][0], __ATOMIC_RELAXED, __HIP_MEMORY_SCOPE_SYSTEM) - (ep + 1u)) < 0)
        __builtin_amdgcn_s_sleep(1);
    }
    asm volatile("" ::: "memory");
  }
  __syncthreads();
  __builtin_amdgcn_fence(__ATOMIC_ACQUIRE, "agent");   // inv L1 + XCD L2
}

// Pipelined partial GEMV: NGR groups of 8 k (stride Bc between k).
// h-values: PLAIN cached loads (compiler clusters + batches vmcnt),
// depth-4 software prefetch. weights: LDS float4 wave-uniform broadcasts.
#define PFD 4
template<int NGR, int P4>
__device__ __forceinline__ void gemv16(const float* __restrict__ src,
                                       const float4* __restrict__ wl4,
                                       const float4* __restrict__ dl4,
                                       float* __restrict__ part, float& dacc)
{
  float pv[PFD][8];
  #pragma unroll
  for (int d=0; d<PFD && d<NGR; ++d) {
    #pragma unroll
    for (int u=0; u<8; ++u) pv[d][u] = src[(d*8+u)*Bc];
  }
  #pragma unroll
  for (int g=0; g<NGR; ++g) {
    const int cb = g % PFD;
    const float h0=pv[cb][0], h1=pv[cb][1], h2=pv[cb][2], h3=pv[cb][3];
    const float h4=pv[cb][4], h5=pv[cb][5], h6=pv[cb][6], h7=pv[cb][7];
    #pragma unroll
    for (int r=0; r<16; ++r) {
      const float4 wa = wl4[r*P4 + 2*g];
      const float4 wb = wl4[r*P4 + 2*g + 1];
      float p = part[r];
      p = fmaf(h0,wa.x,p); p = fmaf(h1,wa.y,p); p = fmaf(h2,wa.z,p); p = fmaf(h3,wa.w,p);
      p = fmaf(h4,wb.x,p); p = fmaf(h5,wb.y,p); p = fmaf(h6,wb.z,p); p = fmaf(h7,wb.w,p);
      part[r] = p;
    }
    const float4 da = dl4[2*g];
    const float4 db_ = dl4[2*g + 1];
    dacc = fmaf(h0,da.x,dacc);  dacc = fmaf(h1,da.y,dacc);
    dacc = fmaf(h2,da.z,dacc);  dacc = fmaf(h3,da.w,dacc);
    dacc = fmaf(h4,db_.x,dacc); dacc = fmaf(h5,db_.y,dacc);
    dacc = fmaf(h6,db_.z,dacc); dacc = fmaf(h7,db_.w,dacc);
    if (g+PFD < NGR) {
      #pragma unroll
      for (int u=0; u<8; ++u) pv[cb][u] = src[((g+PFD)*8+u)*Bc];
    }
  }
}

__global__ __launch_bounds__(TPB, 1) void act_lstm_kernel(
    const float* __restrict__ x,   const float* __restrict__ Wih,
    const float* __restrict__ Whh, const float* __restrict__ bih,
    const float* __restrict__ bhh, const float* __restrict__ hw,
    const float* __restrict__ hbp, const float* __restrict__ dw,
    const float* __restrict__ db,  float* __restrict__ out,
    float* __restrict__ ws)
{
  const int w    = blockIdx.x;
  const int tid  = threadIdx.x;
  const int lane = tid & 63;
  const int wid  = __builtin_amdgcn_readfirstlane(tid >> 6); // 0..15
  const int bh   = wid & 1;
  const int k8   = wid >> 1;         // 0..7 : k-eighth (h) / i-eighth (x)
  const int b    = bh*64 + lane;
  const int jb   = w * 4;            // block owns j = jb..jb+3
  const int jpair= k8 & 3;           // cell ownership for wid<8
  const int jmine= jb + jpair;       // valid for wid<8
  const int kq   = k8 * 64;          // h/st k-slice base
  const int iq   = k8 * 32;          // x i-slice base
  const bool cellw = (wid < 8);

  float* xs   = ws + XS_OFF;
  float* hbuf = ws + HB_OFF;
  float* stc  = ws + SC_OFF;
  float* hpp  = ws + HP_OFF;

  __shared__ __align__(16) float lds_whh[16*512];   // 32 KB
  __shared__ __align__(16) float lds_wih[16*256];   // 16 KB
  __shared__ __align__(16) float lds_wd[512];       //  2 KB
  __shared__ float lds_red[8*8*128];                // 32 KB
  __shared__ float lds_hp[4*128];
  __shared__ float lds_hq[8*128];
  __shared__ float lds_pmh[128];
  __shared__ float lds_dec[8*128];
  __shared__ unsigned lds_u[2];

  // -------- one-time: stage this block's weight rows into LDS --------
  #pragma unroll
  for (int u=0; u<8; ++u) {
    int idx = u*1024 + tid;                 // 0..8191
    int r = idx >> 9, k = idx & 511;
    int grow = (r>>2)*512 + jb + (r&3);
    lds_whh[idx] = Whh[grow*Hc + k];
  }
  #pragma unroll
  for (int u=0; u<4; ++u) {
    int idx = u*1024 + tid;                 // 0..4095
    int r = idx >> 8, k = idx & 255;
    int grow = (r>>2)*512 + jb + (r&3);
    lds_wih[idx] = Wih[grow*Ic + k];
  }
  if (tid < 512) lds_wd[tid] = dw[(w < NCc ? w : 0)*Hc + tid];
  __syncthreads();

  const float4* wh4 = reinterpret_cast<const float4*>(lds_whh) + (kq>>2); // row pitch 128 f4
  const float4* wx4 = reinterpret_cast<const float4*>(lds_wih) + (iq>>2); // row pitch 64 f4
  const float4* wdh = reinterpret_cast<const float4*>(lds_wd)  + (kq>>2);
  const float4* wdx = reinterpret_cast<const float4*>(lds_wd)  + (iq>>2);

  float bsum[4];
  #pragma unroll
  for (int ty=0; ty<4; ++ty) bsum[ty] = bih[ty*512 + jmine] + bhh[ty*512 + jmine];
  const float hwj = hw[jmine];
  const float hb0 = hbp[0];
  const float dbv = db[w < NCc ? w : 0];

  // -------- prologue: stage x[:,:,0] --------
  if (tid < 256) {
    int g = w*256 + tid;             // 128*256 = 32768 = XSZ
    int i = g >> 7, bb = g & 127;
    gstore(xs + i*Bc + bb, x[bb*(Ic*Tc) + i*Tc + 0]);
  }
  gsync(w);

  // -------- persistent state --------
  float c = 0.f;                      // cell (jmine, b) for wid<8
  float st_run=0.f, ct_run=0.f, prev_pm=0.f;
  float cumw=0.f, prevw=0.f, ntfw=0.f, rtvw=0.f, psumw=0.f;  // wid<2: b'=wid*64+lane
  bool  ntsetw=false;
  int   gt = 0;
  int   lastpar = 0;

  for (int t=0; t<Tc; ++t) {
    float xg[4];
    for (int mm=0;; ++mm) {
      float part[16];
      float hacc[4];
      float dacc = 0.f;

      // ---------- phase A ----------
      if (mm == 0) {
        // x-GEMV
        #pragma unroll
        for (int r=0; r<16; ++r) part[r]=0.f;
        {
          float jnk = 0.f;
          gemv16<4,64>(xs + (t&1)*XSZ + iq*Bc + b, wx4, wdx, part, jnk);
        }
        // reduce x partials, 2 chunks of 8 rows
        #pragma unroll
        for (int ch=0; ch<2; ++ch) {
          #pragma unroll
          for (int rr=0; rr<8; ++rr) lds_red[(k8*8+rr)*128 + b] = part[ch*8+rr];
          __syncthreads();
          if (cellw) {
            #pragma unroll
            for (int tt=0; tt<2; ++tt) {
              const int ty = ch*2+tt;
              const int rr = (ty*4+jpair) & 7;
              float s=0.f;
              #pragma unroll
              for (int kk8=0; kk8<8; ++kk8) s += lds_red[(kk8*8+rr)*128 + b];
              xg[ty] = bsum[ty] + s;
            }
          }
          __syncthreads();
        }
        // stage next timestep's x slice
        if (t+1 < Tc && tid < 256) {
          int g = w*256 + tid;
          int i = g >> 7, bb = g & 127;
          gstore(xs + ((t+1)&1)*XSZ + i*Bc + bb, x[bb*(Ic*Tc) + i*Tc + (t+1)]);
        }
        // st-GEMV (h_prev = st(t-1)); decoder dot rides along
        #pragma unroll
        for (int r=0; r<16; ++r) part[r]=0.f;
        if (t > 0) {
          gemv16<8,128>(stc + lastpar*HSZ + kq*Bc + b, wh4, wdh, part, dacc);
        }
      } else {
        #pragma unroll
        for (int r=0; r<16; ++r) part[r]=0.f;
        float jnk = 0.f;
        gemv16<8,128>(hbuf + ((gt-1)&1)*HSZ + kq*Bc + b, wh4, wdh, part, jnk);
      }

      // ---------- reduce h/st partials (2 chunks), + decoder ----------
      if (mm == 0) lds_dec[k8*128 + b] = dacc;
      #pragma unroll
      for (int ch=0; ch<2; ++ch) {
        #pragma unroll
        for (int rr=0; rr<8; ++rr) lds_red[(k8*8+rr)*128 + b] = part[ch*8+rr];
        __syncthreads();
        if (cellw) {
          #pragma unroll
          for (int tt=0; tt<2; ++tt) {
            const int ty = ch*2+tt;
            const int rr = (ty*4+jpair) & 7;
            float s=0.f;
            #pragma unroll
            for (int kk8=0; kk8<8; ++kk8) s += lds_red[(kk8*8+rr)*128 + b];
            hacc[ty] = s;
          }
        }
        __syncthreads();
      }
      if (mm==0 && t>0 && w<NCc && wid<2) {
        const int b2 = wid*64+lane;
        float y=0.f;
        #pragma unroll
        for (int q=0; q<8; ++q) y += lds_dec[q*128 + b2];
        out[(b2*NCc + w)*Tc + (t-1)] = y + dbv;
      }

      // ---------- LSTM cell (i,f,g,o) ----------
      float hn=0.f, cn=0.f;
      if (cellw) {
        float ig = sigm(xg[0]+hacc[0]);
        float fg = sigm(xg[1]+hacc[1]);
        float gg = tanhf(xg[2]+hacc[2]);
        float og = sigm(xg[3]+hacc[3]);
        cn = fg*c + ig*gg;
        hn = og*tanhf(cn);
        gstore(hbuf + (gt&1)*HSZ + jmine*Bc + b, hn);
        gstore(stc  + (gt&1)*HSZ + jmine*Bc + b, st_run + (1.f - prev_pm)*hn);
        lds_hp[jpair*128 + b] = hn*hwj;
      }
      __syncthreads();
      if (wid < 2) {
        const int b2 = wid*64+lane;
        float h4 = (lds_hp[b2]+lds_hp[128+b2])+(lds_hp[256+b2]+lds_hp[384+b2]);
        gstore(hpp + (gt&1)*PSZ + w*Bc + b2, h4);
      }

      gsync(w);

      // ---------- phase B: replicated halting decision ----------
      {
        const int q = wid >> 1, bh2 = wid & 1;
        const int b2 = bh2*64 + lane;
        const float* hp = hpp + (gt&1)*PSZ + q*16*Bc + b2;
        float s0=0.f, s1=0.f, s2=0.f, s3=0.f;
        #pragma unroll
        for (int i4=0; i4<16; i4+=4) {
          s0 += hp[(i4+0)*Bc];
          s1 += hp[(i4+1)*Bc];
          s2 += hp[(i4+2)*Bc];
          s3 += hp[(i4+3)*Bc];
        }
        lds_hq[q*128 + b2] = (s0+s1)+(s2+s3);
      }
      __syncthreads();
      if (wid < 2) {
        const int b2 = wid*64+lane;
        float hpv=0.f;
        #pragma unroll
        for (int q=0; q<8; ++q) hpv += lds_hq[q*128 + b2];
        float pn = sigm(hpv + hb0);
        cumw += pn;
        int ok = __all(cumw >= 0.99f) ? 1 : 0;
        if (lane == 0) lds_u[wid] = (unsigned)ok;
        lds_pmh[b2] = fminf(1.f, cumw);
      }
      __syncthreads();
      int finv = (((lds_u[0] & lds_u[1]) != 0u) || (mm == Mc-1)) ? 1 : 0;

      if (wid < 2) {
        float pmf = finv ? 1.f : fminf(1.f, cumw);
        if (!ntsetw && pmf >= 1.f) {
          ntfw = (float)mm;
          rtvw = (mm == 0) ? 0.f : (1.f - prevw);
          ntsetw = true;
        }
        prevw = pmf;
      }
      if (cellw) {
        float pm = finv ? 1.f : lds_pmh[b];
        float ph = pm - prev_pm;
        st_run += ph*hn;
        ct_run += ph*cn;
        prev_pm = pm;
        c = finv ? ct_run : cn;
      }
      if (finv) {
        if (wid < 2) {
          psumw += ntfw + rtvw;
          if (w == 0) out[N_OFF + (wid*64+lane)*Tc + t] = ntfw;
          ntsetw=false; prevw=0.f; cumw=0.f; ntfw=0.f; rtvw=0.f;
        }
        if (cellw) { st_run=0.f; ct_run=0.f; prev_pm=0.f; }
        lastpar = gt & 1;
        ++gt;
        break;
      }
      ++gt;
    }
  }

  // -------- epilogue: Y for t=23, P --------
  if (w < NCc) {
    float da = 0.f;
    const float* hs = stc + lastpar*HSZ + kq*Bc + b;
    #pragma unroll
    for (int kk=0; kk<64; ++kk) da = fmaf(hs[kk*Bc], lds_wd[kq + kk], da);
    __syncthreads();
    lds_dec[k8*128 + b] = da;
    __syncthreads();
    if (wid < 2) {
      const int b2 = wid*64+lane;
      float y=0.f;
      #pragma unroll
      for (int q=0; q<8; ++q) y += lds_dec[q*128 + b2];
      out[(b2*NCc + w)*Tc + (Tc-1)] = y + dbv;
    }
  }
  if (w == 20 && wid < 2) out[P_OFF + wid*64 + lane] = psumw;
}

extern "C" void kernel_launch(void* const* d_in, const int* in_sizes, int n_in,
                              void* d_out, int out_size, void* d_ws, size_t ws_size,
                              hipStream_t stream) {
  const float* x   = (const float*)d_in[0];
  const float* Wih = (const float*)d_in[1];
  const float* Whh = (const float*)d_in[2];
  const float* bih = (const float*)d_in[3];
  const float* bhh = (const float*)d_in[4];
  const float* hw  = (const float*)d_in[5];
  const float* hb  = (const float*)d_in[6];
  const float* dwp = (const float*)d_in[7];
  const float* dbp = (const float*)d_in[8];
  float* out = (float*)d_out;
  float* ws  = (float*)d_ws;

  void* kargs[] = {(void*)&x, (void*)&Wih, (void*)&Whh, (void*)&bih, (void*)&bhh,
                   (void*)&hw, (void*)&hb, (void*)&dwp, (void*)&dbp, (void*)&out, (void*)&ws};
  hipLaunchCooperativeKernel((void*)act_lstm_kernel, dim3(NWG), dim3(TPB),
                             kargs, 0, stream);
}

// Round 9
// 3969.329 us; speedup vs baseline: 1.1239x; 1.1239x over previous
//
#include <hip/hip_runtime.h>
#include <math.h>

#define NWG 128
#define TPB 1024

static constexpr int Bc=128, Ic=256, Hc=512, NCc=16, Tc=24, Mc=14;
static constexpr int Y_SZ  = Bc*NCc*Tc;     // 49152
static constexpr int P_OFF = Y_SZ;          // 49152
static constexpr int N_OFF = Y_SZ + Bc;     // 49280

// ws layout (floats) -- total 360448 floats = 1.375 MiB (proven budget)
static constexpr int XSZ    = Ic*Bc;                 // 32768
static constexpr int HSZ    = Hc*Bc;                 // 65536
static constexpr int PSZ    = Bc*Bc;                 // 16384
static constexpr int XS_OFF = 0;                     // xs[2][256][128]
static constexpr int HB_OFF = XS_OFF + 2*XSZ;        // hbuf[2][512][128]
static constexpr int SC_OFF = HB_OFF + 2*HSZ;        // stc[2][512][128]
static constexpr int HP_OFF = SC_OFF + 2*HSZ;        // hpp[2][128][128]

// Hierarchical barrier: 16 groups x 8 blocks; monotonic watermarks, 64B lines.
__device__ __align__(64) unsigned g_bcnt[16][16];
__device__ __align__(64) unsigned g_bgen[16][16];
__device__ __align__(64) unsigned g_brc[16];
__device__ __align__(64) unsigned g_brg[16];

__device__ __forceinline__ float sigm(float v){ return 1.0f/(1.0f+expf(-v)); }

// PRODUCER: system-scope write-through stores (sc0 sc1) -> coherent at IF.
__device__ __forceinline__ void gstore(float* p, float v){
  __hip_atomic_store(p, v, __ATOMIC_RELAXED, __HIP_MEMORY_SCOPE_SYSTEM);
}

// CONSUMER: volatile loads. On gfx940+ volatile global accesses lower with
// sc0 sc1 (bypass L1 + non-coherent per-XCD L2, read at the coherent IF),
// but remain ordinary register-allocated loads: the compiler clusters them
// and covers them with counted vmcnt -> they pipeline, unlike atomic loads
// (r5, serialized) and unlike a full-cache-invalidate fence (r6, nukes the
// weight working set every tick). NO fence needed for data coherence.
__device__ __forceinline__ float gload(const float* p){
  return *(const volatile float*)p;
}

// Two-level generation barrier (r6-proven). No cache fence: data coherence
// comes entirely from the sc0/sc1 store + volatile load path.
__device__ __forceinline__ void gsync(int w){
  __syncthreads();
  if (threadIdx.x == 0) {
    asm volatile("" ::: "memory");
    const int g = w >> 3;                    // 16 groups of 8
    unsigned prev = __hip_atomic_fetch_add(&g_bcnt[g][0], 1u, __ATOMIC_RELAXED, __HIP_MEMORY_SCOPE_SYSTEM);
    unsigned ep   = prev >> 3;               // barrier episode
    if ((prev & 7u) == 7u) {
      unsigned rprev = __hip_atomic_fetch_add(&g_brc[0], 1u, __ATOMIC_RELAXED, __HIP_MEMORY_SCOPE_SYSTEM);
      if ((rprev & 15u) == 15u) {
        __hip_atomic_store(&g_brg[0], (rprev >> 4) + 1u, __ATOMIC_RELEASE, __HIP_MEMORY_SCOPE_SYSTEM);
      } else {
        while ((int)(__hip_atomic_load(&g_brg[0], __ATOMIC_RELAXED, __HIP_MEMORY_SCOPE_SYSTEM) - (ep + 1u)) < 0)
          __builtin_amdgcn_s_sleep(1);
      }
      __hip_atomic_store(&g_bgen[g][0], ep + 1u, __ATOMIC_RELEASE, __HIP_MEMORY_SCOPE_SYSTEM);
    } else {
      while ((int)(__hip_atomic_load(&g_bgen[g][0], __ATOMIC_RELAXED, __HIP_MEMORY_SCOPE_SYSTEM) - (ep + 1u)) < 0)
        __builtin_amdgcn_s_sleep(1);
    }
    asm volatile("" ::: "memory");
  }
  __syncthreads();
}

// Partial GEMV over this wave's slice: NGR groups of 8, depth-4 software
// prefetch. h-values: volatile sc0/sc1 loads (pipelined). Weights: plain
// cached loads -- they stay hot in L1/L2 across ticks (no fence, no inval).
#define PFD 4
#define GEMM_BODY(NGR, SRC, WR, DWP)                                          \
  {                                                                           \
    float pv[PFD][8];                                                         \
    _Pragma("unroll")                                                         \
    for (int d=0; d<PFD && d<(NGR); ++d) {                                    \
      _Pragma("unroll")                                                       \
      for (int u=0; u<8; ++u) pv[d][u] = gload((SRC) + (d*8+u)*Bc);           \
    }                                                                         \
    _Pragma("unroll")                                                         \
    for (int it=0; it<(NGR); ++it) {                                          \
      const int cb = it % PFD;                                                \
      _Pragma("unroll")                                                       \
      for (int u=0; u<8; ++u) {                                               \
        const int kk = it*8+u;                                                \
        float hv = pv[cb][u];                                                 \
        _Pragma("unroll")                                                     \
        for (int r=0; r<16; ++r) part[r] = fmaf(hv, (WR)[r][kk], part[r]);    \
        dacc = fmaf(hv, (DWP)[kk], dacc);                                     \
      }                                                                       \
      if (it+PFD < (NGR)) {                                                   \
        _Pragma("unroll")                                                     \
        for (int u=0; u<8; ++u) pv[cb][u] = gload((SRC) + ((it+PFD)*8+u)*Bc); \
      }                                                                       \
    }                                                                         \
  }

__global__ __launch_bounds__(TPB, 1) void act_lstm_kernel(
    const float* __restrict__ x,   const float* __restrict__ Wih,
    const float* __restrict__ Whh, const float* __restrict__ bih,
    const float* __restrict__ bhh, const float* __restrict__ hw,
    const float* __restrict__ hbp, const float* __restrict__ dw,
    const float* __restrict__ db,  float* __restrict__ out,
    float* __restrict__ ws)
{
  const int w    = blockIdx.x;
  const int tid  = threadIdx.x;
  const int lane = tid & 63;
  const int wid  = __builtin_amdgcn_readfirstlane(tid >> 6); // 0..15
  const int bh   = wid & 1;
  const int k8   = wid >> 1;         // 0..7 : k-eighth (h) / i-eighth (x)
  const int b    = bh*64 + lane;
  const int jb   = w * 4;            // block owns j = jb..jb+3
  const int jpair= k8 & 3;           // cell ownership for wid<8
  const int jmine= jb + jpair;       // valid for wid<8
  const int kq   = k8 * 64;          // h/st k-slice base
  const int iq   = k8 * 32;          // x i-slice base
  const bool cellw = (wid < 8);

  float* xs   = ws + XS_OFF;
  float* hbuf = ws + HB_OFF;
  float* stc  = ws + SC_OFF;
  float* hpp  = ws + HP_OFF;

  __shared__ float lds_red[8*8*128];   // [k8][row-chunk 8][b] = 32 KB
  __shared__ float lds_hp[4*128];
  __shared__ float lds_hq[8*128];
  __shared__ float lds_pmh[128];
  __shared__ float lds_dec[8*128];
  __shared__ unsigned lds_u[2];

  const float* whp[16];
  const float* wip[16];
  #pragma unroll
  for (int r=0; r<16; ++r) {
    const int grow = (r>>2)*512 + jb + (r&3);
    whp[r] = Whh + grow*Hc + kq;
    wip[r] = Wih + grow*Ic + iq;
  }
  float bsum[4];
  #pragma unroll
  for (int ty=0; ty<4; ++ty) bsum[ty] = bih[ty*512 + jmine] + bhh[ty*512 + jmine];
  const float hwj = hw[jmine];
  const float hb0 = hbp[0];
  const float* dwq = dw + (w < NCc ? w : 0)*Hc + kq;   // decoder class = w for w<16
  const float dbv  = db[w < NCc ? w : 0];

  // -------- prologue: stage x[:,:,0] --------
  if (tid < 256) {
    int g = w*256 + tid;             // 128*256 = 32768 = XSZ
    int i = g >> 7, bb = g & 127;
    gstore(xs + i*Bc + bb, x[bb*(Ic*Tc) + i*Tc + 0]);
  }
  gsync(w);

  // -------- persistent state --------
  float c = 0.f;                      // cell (jmine, b) for wid<8
  float st_run=0.f, ct_run=0.f, prev_pm=0.f;
  float cumw=0.f, prevw=0.f, ntfw=0.f, rtvw=0.f, psumw=0.f;  // wid<2: b'=wid*64+lane
  bool  ntsetw=false;
  int   gt = 0;
  int   lastpar = 0;

  for (int t=0; t<Tc; ++t) {
    float xg[4];
    for (int mm=0;; ++mm) {
      float part[16];
      float hacc[4];
      float dacc = 0.f;

      // ---------- phase A ----------
      if (mm == 0) {
        // x-GEMV
        #pragma unroll
        for (int r=0; r<16; ++r) part[r]=0.f;
        {
          const float* xsr = xs + (t&1)*XSZ + iq*Bc + b;
          GEMM_BODY(4, xsr, wip, dwq)
        }
        dacc = 0.f;
        // reduce x partials, 2 chunks of 8 rows
        #pragma unroll
        for (int ch=0; ch<2; ++ch) {
          #pragma unroll
          for (int rr=0; rr<8; ++rr) lds_red[(k8*8+rr)*128 + b] = part[ch*8+rr];
          __syncthreads();
          if (cellw) {
            #pragma unroll
            for (int tt=0; tt<2; ++tt) {
              const int ty = ch*2+tt;
              const int rr = (ty*4+jpair) & 7;
              float s=0.f;
              #pragma unroll
              for (int kk8=0; kk8<8; ++kk8) s += lds_red[(kk8*8+rr)*128 + b];
              xg[ty] = bsum[ty] + s;
            }
          }
          __syncthreads();
        }
        // stage next timestep's x slice
        if (t+1 < Tc && tid < 256) {
          int g = w*256 + tid;
          int i = g >> 7, bb = g & 127;
          gstore(xs + ((t+1)&1)*XSZ + i*Bc + bb, x[bb*(Ic*Tc) + i*Tc + (t+1)]);
        }
        // st-GEMV (h_prev = st(t-1)); decoder dot rides along
        #pragma unroll
        for (int r=0; r<16; ++r) part[r]=0.f;
        if (t > 0) {
          const float* hs = stc + lastpar*HSZ + kq*Bc + b;
          GEMM_BODY(8, hs, whp, dwq)
        }
      } else {
        #pragma unroll
        for (int r=0; r<16; ++r) part[r]=0.f;
        const float* hs = hbuf + ((gt-1)&1)*HSZ + kq*Bc + b;
        GEMM_BODY(8, hs, whp, dwq)
      }

      // ---------- reduce h/st partials (2 chunks), + decoder ----------
      if (mm == 0) lds_dec[k8*128 + b] = dacc;
      #pragma unroll
      for (int ch=0; ch<2; ++ch) {
        #pragma unroll
        for (int rr=0; rr<8; ++rr) lds_red[(k8*8+rr)*128 + b] = part[ch*8+rr];
        __syncthreads();
        if (cellw) {
          #pragma unroll
          for (int tt=0; tt<2; ++tt) {
            const int ty = ch*2+tt;
            const int rr = (ty*4+jpair) & 7;
            float s=0.f;
            #pragma unroll
            for (int kk8=0; kk8<8; ++kk8) s += lds_red[(kk8*8+rr)*128 + b];
            hacc[ty] = s;
          }
        }
        __syncthreads();
      }
      if (mm==0 && t>0 && w<NCc && wid<2) {
        const int b2 = wid*64+lane;
        float y=0.f;
        #pragma unroll
        for (int q=0; q<8; ++q) y += lds_dec[q*128 + b2];
        out[(b2*NCc + w)*Tc + (t-1)] = y + dbv;
      }

      // ---------- LSTM cell (i,f,g,o) ----------
      float hn=0.f, cn=0.f;
      if (cellw) {
        float ig = sigm(xg[0]+hacc[0]);
        float fg = sigm(xg[1]+hacc[1]);
        float gg = tanhf(xg[2]+hacc[2]);
        float og = sigm(xg[3]+hacc[3]);
        cn = fg*c + ig*gg;
        hn = og*tanhf(cn);
        gstore(hbuf + (gt&1)*HSZ + jmine*Bc + b, hn);
        gstore(stc  + (gt&1)*HSZ + jmine*Bc + b, st_run + (1.f - prev_pm)*hn);
        lds_hp[jpair*128 + b] = hn*hwj;
      }
      __syncthreads();
      if (wid < 2) {
        const int b2 = wid*64+lane;
        float h4 = (lds_hp[b2]+lds_hp[128+b2])+(lds_hp[256+b2]+lds_hp[384+b2]);
        gstore(hpp + (gt&1)*PSZ + w*Bc + b2, h4);
      }

      gsync(w);

      // ---------- phase B: replicated halting decision ----------
      {
        const int q = wid >> 1, bh2 = wid & 1;
        const int b2 = bh2*64 + lane;
        const float* hp = hpp + (gt&1)*PSZ + q*16*Bc + b2;
        float s0=0.f, s1=0.f, s2=0.f, s3=0.f;
        #pragma unroll
        for (int i4=0; i4<16; i4+=4) {
          s0 += gload(hp + (i4+0)*Bc);
          s1 += gload(hp + (i4+1)*Bc);
          s2 += gload(hp + (i4+2)*Bc);
          s3 += gload(hp + (i4+3)*Bc);
        }
        lds_hq[q*128 + b2] = (s0+s1)+(s2+s3);
      }
      __syncthreads();
      if (wid < 2) {
        const int b2 = wid*64+lane;
        float hpv=0.f;
        #pragma unroll
        for (int q=0; q<8; ++q) hpv += lds_hq[q*128 + b2];
        float pn = sigm(hpv + hb0);
        cumw += pn;
        int ok = __all(cumw >= 0.99f) ? 1 : 0;
        if (lane == 0) lds_u[wid] = (unsigned)ok;
        lds_pmh[b2] = fminf(1.f, cumw);
      }
      __syncthreads();
      int finv = (((lds_u[0] & lds_u[1]) != 0u) || (mm == Mc-1)) ? 1 : 0;

      if (wid < 2) {
        float pmf = finv ? 1.f : fminf(1.f, cumw);
        if (!ntsetw && pmf >= 1.f) {
          ntfw = (float)mm;
          rtvw = (mm == 0) ? 0.f : (1.f - prevw);
          ntsetw = true;
        }
        prevw = pmf;
      }
      if (cellw) {
        float pm = finv ? 1.f : lds_pmh[b];
        float ph = pm - prev_pm;
        st_run += ph*hn;
        ct_run += ph*cn;
        prev_pm = pm;
        c = finv ? ct_run : cn;
      }
      if (finv) {
        if (wid < 2) {
          psumw += ntfw + rtvw;
          if (w == 0) out[N_OFF + (wid*64+lane)*Tc + t] = ntfw;
          ntsetw=false; prevw=0.f; cumw=0.f; ntfw=0.f; rtvw=0.f;
        }
        if (cellw) { st_run=0.f; ct_run=0.f; prev_pm=0.f; }
        lastpar = gt & 1;
        ++gt;
        break;
      }
      ++gt;
    }
  }

  // -------- epilogue: Y for t=23, P --------
  if (w < NCc) {
    float da = 0.f;
    const float* hs = stc + lastpar*HSZ + kq*Bc + b;
    #pragma unroll
    for (int kk=0; kk<64; ++kk) da = fmaf(gload(hs + kk*Bc), dwq[kk], da);
    __syncthreads();
    lds_dec[k8*128 + b] = da;
    __syncthreads();
    if (wid < 2) {
      const int b2 = wid*64+lane;
      float y=0.f;
      #pragma unroll
      for (int q=0; q<8; ++q) y += lds_dec[q*128 + b2];
      out[(b2*NCc + w)*Tc + (Tc-1)] = y + dbv;
    }
  }
  if (w == 20 && wid < 2) out[P_OFF + wid*64 + lane] = psumw;
}

extern "C" void kernel_launch(void* const* d_in, const int* in_sizes, int n_in,
                              void* d_out, int out_size, void* d_ws, size_t ws_size,
                              hipStream_t stream) {
  const float* x   = (const float*)d_in[0];
  const float* Wih = (const float*)d_in[1];
  const float* Whh = (const float*)d_in[2];
  const float* bih = (const float*)d_in[3];
  const float* bhh = (const float*)d_in[4];
  const float* hw  = (const float*)d_in[5];
  const float* hb  = (const float*)d_in[6];
  const float* dwp = (const float*)d_in[7];
  const float* dbp = (const float*)d_in[8];
  float* out = (float*)d_out;
  float* ws  = (float*)d_ws;

  void* kargs[] = {(void*)&x, (void*)&Wih, (void*)&Whh, (void*)&bih, (void*)&bhh,
                   (void*)&hw, (void*)&hb, (void*)&dwp, (void*)&dbp, (void*)&out, (void*)&ws};
  hipLaunchCooperativeKernel((void*)act_lstm_kernel, dim3(NWG), dim3(TPB),
                             kargs, 0, stream);
}